// Round 2
// baseline (578.243 us; speedup 1.0000x reference)
//
#include <hip/hip_runtime.h>
#include <hip/hip_bf16.h>
#include <stdint.h>

typedef __bf16 bf16x8 __attribute__((ext_vector_type(8)));
typedef float f32x4 __attribute__((ext_vector_type(4)));
typedef unsigned short u16;
typedef u16 u16x8 __attribute__((ext_vector_type(8)));

__device__ __forceinline__ float bf2f(u16 u) {
  union { uint32_t i; float f; } v; v.i = uint32_t(u) << 16; return v.f;
}
__device__ __forceinline__ u16 f2bf(float f) {
  union { float f; uint32_t i; } v; v.f = f;
  uint32_t r = v.i + 0x7FFFu + ((v.i >> 16) & 1u);  // RNE
  return (u16)(r >> 16);
}

// ---------------------------------------------------------------------------
// f32 -> bf16 conversion (inputs arrive as float32; we compute in bf16)
// ---------------------------------------------------------------------------
__global__ __launch_bounds__(256) void f32_to_bf16(
    const float* __restrict__ in, u16* __restrict__ out, int n)
{
  const int i = (blockIdx.x * 256 + threadIdx.x) * 8;
  if (i >= n) return;
  const float4 a = *reinterpret_cast<const float4*>(in + i);
  const float4 b = *reinterpret_cast<const float4*>(in + i + 4);
  u16x8 o;
  o[0] = f2bf(a.x); o[1] = f2bf(a.y); o[2] = f2bf(a.z); o[3] = f2bf(a.w);
  o[4] = f2bf(b.x); o[5] = f2bf(b.y); o[6] = f2bf(b.z); o[7] = f2bf(b.w);
  *reinterpret_cast<u16x8*>(out + i) = o;
}

// ---------------------------------------------------------------------------
// GEMM: C[M,N] = A[M,K] * B[N,K]^T   (both operands K-major, bf16, f32 acc)
// 128x128 tile, BK=32, 4 waves (2x2), each wave 4x4 16x16x32 MFMA fragments.
// LDS row stride 40 elems (80B) -> only 2-way bank aliasing (free).
// F32OUT: store C as float (final projection writes d_out), else bf16.
// ---------------------------------------------------------------------------
#define BM 128
#define BN 128
#define BK 32
#define LDS_STR 40

template <int F32OUT>
__global__ __launch_bounds__(256) void gemm_bt(
    const u16* __restrict__ A, const u16* __restrict__ Bw, void* __restrict__ Cv,
    int N, int K)
{
  __shared__ u16 As[BM * LDS_STR];
  __shared__ u16 Bs[BN * LDS_STR];
  const int tid = threadIdx.x;
  const int row0 = blockIdx.y * BM, col0 = blockIdx.x * BN;
  const int wv = tid >> 6, lane = tid & 63;
  const int wr = (wv >> 1) * 64, wc = (wv & 1) * 64;
  const int l15 = lane & 15, lk = (lane >> 4) * 8;
  const int srow = tid >> 2, sk = (tid & 3) * 8;

  f32x4 acc[4][4] = {};

  for (int k0 = 0; k0 < K; k0 += BK) {
    bf16x8 av0 = *reinterpret_cast<const bf16x8*>(A + (size_t)(row0 + srow) * K + k0 + sk);
    bf16x8 av1 = *reinterpret_cast<const bf16x8*>(A + (size_t)(row0 + srow + 64) * K + k0 + sk);
    bf16x8 bv0 = *reinterpret_cast<const bf16x8*>(Bw + (size_t)(col0 + srow) * K + k0 + sk);
    bf16x8 bv1 = *reinterpret_cast<const bf16x8*>(Bw + (size_t)(col0 + srow + 64) * K + k0 + sk);
    *reinterpret_cast<bf16x8*>(As + srow * LDS_STR + sk) = av0;
    *reinterpret_cast<bf16x8*>(As + (srow + 64) * LDS_STR + sk) = av1;
    *reinterpret_cast<bf16x8*>(Bs + srow * LDS_STR + sk) = bv0;
    *reinterpret_cast<bf16x8*>(Bs + (srow + 64) * LDS_STR + sk) = bv1;
    __syncthreads();

    bf16x8 af[4], bfv[4];
#pragma unroll
    for (int i = 0; i < 4; ++i)
      af[i] = *reinterpret_cast<const bf16x8*>(As + (wr + i * 16 + l15) * LDS_STR + lk);
#pragma unroll
    for (int i = 0; i < 4; ++i)
      bfv[i] = *reinterpret_cast<const bf16x8*>(Bs + (wc + i * 16 + l15) * LDS_STR + lk);
#pragma unroll
    for (int mi = 0; mi < 4; ++mi)
#pragma unroll
      for (int ni = 0; ni < 4; ++ni)
        acc[mi][ni] = __builtin_amdgcn_mfma_f32_16x16x32_bf16(af[mi], bfv[ni], acc[mi][ni], 0, 0, 0);
    __syncthreads();
  }

  // C/D layout: col = lane&15, row = (lane>>4)*4 + reg  [verified m89/m91]
#pragma unroll
  for (int mi = 0; mi < 4; ++mi) {
    const int r0 = row0 + wr + mi * 16 + (lane >> 4) * 4;
#pragma unroll
    for (int ni = 0; ni < 4; ++ni) {
      const int c = col0 + wc + ni * 16 + l15;
#pragma unroll
      for (int r = 0; r < 4; ++r) {
        if (F32OUT)
          reinterpret_cast<float*>(Cv)[(size_t)(r0 + r) * N + c] = acc[mi][ni][r];
        else
          reinterpret_cast<u16*>(Cv)[(size_t)(r0 + r) * N + c] = f2bf(acc[mi][ni][r]);
      }
    }
  }
}

// ---------------------------------------------------------------------------
// RoPE, in-place on Q (4096x2048) then K (4096x512). 8 bf16 (4 pairs)/thread.
// cos/sin tables are float32 inputs.
// ---------------------------------------------------------------------------
__global__ __launch_bounds__(256) void rope_kernel(
    u16* __restrict__ Q, u16* __restrict__ Kv,
    const float* __restrict__ cosb, const float* __restrict__ sinb)
{
  const int QV = 4096 * 2048 / 8;   // 1048576 vec8 groups
  const int KV = 4096 * 512 / 8;    // 262144
  int t = blockIdx.x * 256 + threadIdx.x;
  u16* ptr; int shift;
  if (t < QV) { ptr = Q; shift = 11; }
  else { t -= QV; if (t >= KV) return; ptr = Kv; shift = 9; }
  const int e = t * 8;
  const int row = e >> shift;           // m = b*2048 + s
  const int col = e & ((1 << shift) - 1);
  const int s = row & 2047;
  const int j0 = (col & 63) >> 1;       // pair index within head (multiple of 4)
  u16* p = ptr + ((size_t)row << shift) + col;
  u16x8 x = *reinterpret_cast<const u16x8*>(p);
  u16x8 o;
#pragma unroll
  for (int q = 0; q < 4; ++q) {
    const float c  = cosb[s * 32 + j0 + q];
    const float sn = sinb[s * 32 + j0 + q];
    const float xr = bf2f(x[2 * q]), xi = bf2f(x[2 * q + 1]);
    o[2 * q]     = f2bf(xr * c - xi * sn);
    o[2 * q + 1] = f2bf(xr * sn + xi * c);
  }
  *reinterpret_cast<u16x8*>(p) = o;
}

// ---------------------------------------------------------------------------
// Causal flash attention, GQA (4 q-heads per kv-head).
// Grid: (S/64, NH, B). Block: 256 (4 waves), wave owns 16 q rows.
// K tile 32x64 in LDS (stride 72), V tile transposed 64x32 (stride 40).
// Online softmax via 16-lane shfl_xor reductions; P via per-wave LDS buffer.
// ---------------------------------------------------------------------------
__global__ __launch_bounds__(256) void attn_kernel(
    const u16* __restrict__ Q, const u16* __restrict__ K,
    const u16* __restrict__ V, u16* __restrict__ O)
{
  __shared__ u16 Ks[32 * 72];
  __shared__ u16 Vt[64 * 40];
  __shared__ u16 Pl[4][16 * 40];

  const int q0 = blockIdx.x * 64;
  const int h  = blockIdx.y;
  const int b  = blockIdx.z;
  const int kh = h >> 2;                // NREP = 4
  const int tid = threadIdx.x, wv = tid >> 6, lane = tid & 63;
  const int l15 = lane & 15, lhi = lane >> 4;

  const size_t qoff = (size_t)b * 2048 * 2048;
  const size_t koff = (size_t)b * 2048 * 512;

  // Q fragments (A-layout: row = lane&15, k = (lane>>4)*8 + i), 2 k-chunks of 32
  const int qrow = q0 + wv * 16 + l15;
  const bf16x8 qf0 = *reinterpret_cast<const bf16x8*>(Q + qoff + (size_t)qrow * 2048 + h * 64 + lhi * 8);
  const bf16x8 qf1 = *reinterpret_cast<const bf16x8*>(Q + qoff + (size_t)qrow * 2048 + h * 64 + 32 + lhi * 8);

  float m[4], l[4];
  f32x4 oacc[4] = {};
#pragma unroll
  for (int r = 0; r < 4; ++r) { m[r] = -1e30f; l[r] = 0.f; }

  const int qr_base = q0 + wv * 16;
  const int ntiles = (q0 + 64) / 32;
  const int skr = tid >> 3, skc = (tid & 7) * 8;   // K staging
  const int svd = tid >> 2, svt = (tid & 3) * 8;   // V transpose staging

  for (int t = 0; t < ntiles; ++t) {
    const int t0 = t * 32;
    // stage K tile row-major
    *reinterpret_cast<bf16x8*>(Ks + skr * 72 + skc) =
        *reinterpret_cast<const bf16x8*>(K + koff + (size_t)(t0 + skr) * 512 + kh * 64 + skc);
    // stage V tile transposed [d][t]
    u16 tmp[8];
#pragma unroll
    for (int i = 0; i < 8; ++i)
      tmp[i] = V[koff + (size_t)(t0 + svt + i) * 512 + kh * 64 + svd];
#pragma unroll
    for (int i = 0; i < 8; ++i)
      Vt[svd * 40 + svt + i] = tmp[i];
    __syncthreads();

    if (t0 <= qr_base + 15) {  // wave-uniform causal tile skip
      f32x4 s0 = {}, s1 = {};
      {
        bf16x8 kf = *reinterpret_cast<const bf16x8*>(Ks + l15 * 72 + lhi * 8);
        s0 = __builtin_amdgcn_mfma_f32_16x16x32_bf16(qf0, kf, s0, 0, 0, 0);
        kf = *reinterpret_cast<const bf16x8*>(Ks + l15 * 72 + 32 + lhi * 8);
        s0 = __builtin_amdgcn_mfma_f32_16x16x32_bf16(qf1, kf, s0, 0, 0, 0);
        kf = *reinterpret_cast<const bf16x8*>(Ks + (16 + l15) * 72 + lhi * 8);
        s1 = __builtin_amdgcn_mfma_f32_16x16x32_bf16(qf0, kf, s1, 0, 0, 0);
        kf = *reinterpret_cast<const bf16x8*>(Ks + (16 + l15) * 72 + 32 + lhi * 8);
        s1 = __builtin_amdgcn_mfma_f32_16x16x32_bf16(qf1, kf, s1, 0, 0, 0);
      }
      const bool needmask = (t0 + 31) > qr_base;
#pragma unroll
      for (int r = 0; r < 4; ++r) {
        const int qr = qr_base + lhi * 4 + r;     // this lane's C-row
        float v0 = s0[r] * 0.125f, v1 = s1[r] * 0.125f;
        if (needmask) {
          if (t0 + l15 > qr)       v0 = -1e30f;
          if (t0 + 16 + l15 > qr)  v1 = -1e30f;
        }
        float mx = fmaxf(v0, v1);
#pragma unroll
        for (int off = 1; off < 16; off <<= 1) mx = fmaxf(mx, __shfl_xor(mx, off));
        const float newm = fmaxf(m[r], mx);
        const float fac = __expf(m[r] - newm);
        const float p0 = __expf(v0 - newm), p1 = __expf(v1 - newm);
        float sum = p0 + p1;
#pragma unroll
        for (int off = 1; off < 16; off <<= 1) sum += __shfl_xor(sum, off);
        l[r] = l[r] * fac + sum;
        m[r] = newm;
#pragma unroll
        for (int nf = 0; nf < 4; ++nf) oacc[nf][r] *= fac;
        // write P (C-layout) to per-wave LDS for A-frag re-read
        Pl[wv][(lhi * 4 + r) * 40 + l15]      = f2bf(p0);
        Pl[wv][(lhi * 4 + r) * 40 + 16 + l15] = f2bf(p1);
      }
      const bf16x8 pf = *reinterpret_cast<const bf16x8*>(&Pl[wv][l15 * 40 + lhi * 8]);
#pragma unroll
      for (int nf = 0; nf < 4; ++nf) {
        const bf16x8 vf = *reinterpret_cast<const bf16x8*>(Vt + (nf * 16 + l15) * 40 + lhi * 8);
        oacc[nf] = __builtin_amdgcn_mfma_f32_16x16x32_bf16(pf, vf, oacc[nf], 0, 0, 0);
      }
    }
    __syncthreads();
  }

#pragma unroll
  for (int nf = 0; nf < 4; ++nf) {
#pragma unroll
    for (int r = 0; r < 4; ++r) {
      const int qr = q0 + wv * 16 + lhi * 4 + r;
      O[qoff + (size_t)qr * 2048 + h * 64 + nf * 16 + l15] = f2bf(oacc[nf][r] / l[r]);
    }
  }
}

// ---------------------------------------------------------------------------
extern "C" void kernel_launch(void* const* d_in, const int* in_sizes, int n_in,
                              void* d_out, int out_size, void* d_ws, size_t ws_size,
                              hipStream_t stream)
{
  const float* x  = (const float*)d_in[0];
  const float* fc = (const float*)d_in[1];
  const float* fs = (const float*)d_in[2];
  // d_in[3] = mask (causal; implemented analytically)
  const float* wq = (const float*)d_in[4];
  const float* wk = (const float*)d_in[5];
  const float* wv = (const float*)d_in[6];
  const float* wo = (const float*)d_in[7];
  float* out = (float*)d_out;

  // workspace layout (bf16 elements)
  u16* Xb  = (u16*)d_ws;                          // 4096 x 2048 (aliased by Ows later)
  u16* Wqb = Xb  + (size_t)4096 * 2048;           // 2048 x 2048 (aliased by Wob later)
  u16* Wkb = Wqb + (size_t)2048 * 2048;           // 512 x 2048
  u16* Wvb = Wkb + (size_t)512 * 2048;            // 512 x 2048
  u16* Qws = Wvb + (size_t)512 * 2048;            // 4096 x 2048
  u16* Kws = Qws + (size_t)4096 * 2048;           // 4096 x 512
  u16* Vws = Kws + (size_t)4096 * 512;            // 4096 x 512
  u16* Ows = Xb;                                  // alias: x dead after QKV gemms
  u16* Wob = Wqb;                                 // alias: wq dead after Q gemm

  dim3 blk(256);
  // input conversion f32 -> bf16
  f32_to_bf16<<<dim3(4096 * 2048 / 8 / 256), blk, 0, stream>>>(x,  Xb,  4096 * 2048);
  f32_to_bf16<<<dim3(2048 * 2048 / 8 / 256), blk, 0, stream>>>(wq, Wqb, 2048 * 2048);
  f32_to_bf16<<<dim3(512 * 2048 / 8 / 256),  blk, 0, stream>>>(wk, Wkb, 512 * 2048);
  f32_to_bf16<<<dim3(512 * 2048 / 8 / 256),  blk, 0, stream>>>(wv, Wvb, 512 * 2048);
  // QKV projections (A = x flattened to 4096x2048)
  gemm_bt<0><<<dim3(16, 32), blk, 0, stream>>>(Xb, Wqb, Qws, 2048, 2048);
  gemm_bt<0><<<dim3(4, 32),  blk, 0, stream>>>(Xb, Wkb, Kws, 512, 2048);
  gemm_bt<0><<<dim3(4, 32),  blk, 0, stream>>>(Xb, Wvb, Vws, 512, 2048);
  // wo conversion (reuses Wqb region)
  f32_to_bf16<<<dim3(2048 * 2048 / 8 / 256), blk, 0, stream>>>(wo, Wob, 2048 * 2048);
  // RoPE in-place on Q and K
  rope_kernel<<<dim3((4096 * 2048 / 8 + 4096 * 512 / 8) / 256), blk, 0, stream>>>(Qws, Kws, fc, fs);
  // Flash attention -> Ows (aliases Xb)
  attn_kernel<<<dim3(32, 32, 2), blk, 0, stream>>>(Qws, Kws, Vws, Ows);
  // Output projection -> f32 d_out
  gemm_bt<1><<<dim3(16, 32), blk, 0, stream>>>(Ows, Wob, out, 2048, 2048);
}

// Round 3
// 495.072 us; speedup vs baseline: 1.1680x; 1.1680x over previous
//
#include <hip/hip_runtime.h>
#include <hip/hip_bf16.h>
#include <stdint.h>

typedef __bf16 bf16x8 __attribute__((ext_vector_type(8)));
typedef float f32x4 __attribute__((ext_vector_type(4)));
typedef unsigned short u16;
typedef u16 u16x8 __attribute__((ext_vector_type(8)));

__device__ __forceinline__ float bf2f(u16 u) {
  union { uint32_t i; float f; } v; v.i = uint32_t(u) << 16; return v.f;
}
__device__ __forceinline__ u16 f2bf(float f) {
  union { float f; uint32_t i; } v; v.f = f;
  uint32_t r = v.i + 0x7FFFu + ((v.i >> 16) & 1u);  // RNE
  return (u16)(r >> 16);
}

// ---------------------------------------------------------------------------
// f32 -> bf16 conversion
// ---------------------------------------------------------------------------
__global__ __launch_bounds__(256) void f32_to_bf16(
    const float* __restrict__ in, u16* __restrict__ out, int n)
{
  const int i = (blockIdx.x * 256 + threadIdx.x) * 8;
  if (i >= n) return;
  const float4 a = *reinterpret_cast<const float4*>(in + i);
  const float4 b = *reinterpret_cast<const float4*>(in + i + 4);
  u16x8 o;
  o[0] = f2bf(a.x); o[1] = f2bf(a.y); o[2] = f2bf(a.z); o[3] = f2bf(a.w);
  o[4] = f2bf(b.x); o[5] = f2bf(b.y); o[6] = f2bf(b.z); o[7] = f2bf(b.w);
  *reinterpret_cast<u16x8*>(out + i) = o;
}

// ---------------------------------------------------------------------------
// GEMM: C[M,N] = A[M,K] * B[N,K]^T   (bf16 in, f32 acc)
// F32OUT: store C as float. TRANSC: store C transposed (C_T[c*ldc + r], bf16).
// ---------------------------------------------------------------------------
#define BM 128
#define BN 128
#define BK 32
#define LDS_STR 40

template <int F32OUT, int TRANSC>
__global__ __launch_bounds__(256) void gemm_bt(
    const u16* __restrict__ A, const u16* __restrict__ Bw, void* __restrict__ Cv,
    int N, int K, int ldc)
{
  __shared__ u16 As[BM * LDS_STR];
  __shared__ u16 Bs[BN * LDS_STR];
  const int tid = threadIdx.x;
  const int row0 = blockIdx.y * BM, col0 = blockIdx.x * BN;
  const int wv = tid >> 6, lane = tid & 63;
  const int wr = (wv >> 1) * 64, wc = (wv & 1) * 64;
  const int l15 = lane & 15, lk = (lane >> 4) * 8;
  const int srow = tid >> 2, sk = (tid & 3) * 8;

  f32x4 acc[4][4] = {};

  for (int k0 = 0; k0 < K; k0 += BK) {
    bf16x8 av0 = *reinterpret_cast<const bf16x8*>(A + (size_t)(row0 + srow) * K + k0 + sk);
    bf16x8 av1 = *reinterpret_cast<const bf16x8*>(A + (size_t)(row0 + srow + 64) * K + k0 + sk);
    bf16x8 bv0 = *reinterpret_cast<const bf16x8*>(Bw + (size_t)(col0 + srow) * K + k0 + sk);
    bf16x8 bv1 = *reinterpret_cast<const bf16x8*>(Bw + (size_t)(col0 + srow + 64) * K + k0 + sk);
    *reinterpret_cast<bf16x8*>(As + srow * LDS_STR + sk) = av0;
    *reinterpret_cast<bf16x8*>(As + (srow + 64) * LDS_STR + sk) = av1;
    *reinterpret_cast<bf16x8*>(Bs + srow * LDS_STR + sk) = bv0;
    *reinterpret_cast<bf16x8*>(Bs + (srow + 64) * LDS_STR + sk) = bv1;
    __syncthreads();

    bf16x8 af[4], bfv[4];
#pragma unroll
    for (int i = 0; i < 4; ++i)
      af[i] = *reinterpret_cast<const bf16x8*>(As + (wr + i * 16 + l15) * LDS_STR + lk);
#pragma unroll
    for (int i = 0; i < 4; ++i)
      bfv[i] = *reinterpret_cast<const bf16x8*>(Bs + (wc + i * 16 + l15) * LDS_STR + lk);
#pragma unroll
    for (int mi = 0; mi < 4; ++mi)
#pragma unroll
      for (int ni = 0; ni < 4; ++ni)
        acc[mi][ni] = __builtin_amdgcn_mfma_f32_16x16x32_bf16(af[mi], bfv[ni], acc[mi][ni], 0, 0, 0);
    __syncthreads();
  }

  // C/D layout: col = lane&15, row = (lane>>4)*4 + reg
#pragma unroll
  for (int mi = 0; mi < 4; ++mi) {
    const int r0 = row0 + wr + mi * 16 + (lane >> 4) * 4;
#pragma unroll
    for (int ni = 0; ni < 4; ++ni) {
      const int c = col0 + wc + ni * 16 + l15;
#pragma unroll
      for (int r = 0; r < 4; ++r) {
        if (TRANSC)
          reinterpret_cast<u16*>(Cv)[(size_t)c * ldc + (r0 + r)] = f2bf(acc[mi][ni][r]);
        else if (F32OUT)
          reinterpret_cast<float*>(Cv)[(size_t)(r0 + r) * ldc + c] = acc[mi][ni][r];
        else
          reinterpret_cast<u16*>(Cv)[(size_t)(r0 + r) * ldc + c] = f2bf(acc[mi][ni][r]);
      }
    }
  }
}

// ---------------------------------------------------------------------------
// RoPE, in-place on Q (4096x2048) then K (4096x512).
// ---------------------------------------------------------------------------
__global__ __launch_bounds__(256) void rope_kernel(
    u16* __restrict__ Q, u16* __restrict__ Kv,
    const float* __restrict__ cosb, const float* __restrict__ sinb)
{
  const int QV = 4096 * 2048 / 8;
  const int KV = 4096 * 512 / 8;
  int t = blockIdx.x * 256 + threadIdx.x;
  u16* ptr; int shift;
  if (t < QV) { ptr = Q; shift = 11; }
  else { t -= QV; if (t >= KV) return; ptr = Kv; shift = 9; }
  const int e = t * 8;
  const int row = e >> shift;
  const int col = e & ((1 << shift) - 1);
  const int s = row & 2047;
  const int j0 = (col & 63) >> 1;
  u16* p = ptr + ((size_t)row << shift) + col;
  u16x8 x = *reinterpret_cast<const u16x8*>(p);
  u16x8 o;
#pragma unroll
  for (int q = 0; q < 4; ++q) {
    const float c  = cosb[s * 32 + j0 + q];
    const float sn = sinb[s * 32 + j0 + q];
    const float xr = bf2f(x[2 * q]), xi = bf2f(x[2 * q + 1]);
    o[2 * q]     = f2bf(xr * c - xi * sn);
    o[2 * q + 1] = f2bf(xr * sn + xi * c);
  }
  *reinterpret_cast<u16x8*>(p) = o;
}

// ---------------------------------------------------------------------------
// Swizzled-LDS helpers: tiles are [rows][64] bf16, row stride 128B,
// byte ^= ((row&7)<<4)  (T2 st-swizzle: kills stride-128B bank conflicts)
// ---------------------------------------------------------------------------
__device__ __forceinline__ bf16x8 lds_read8(const u16* base, int row, int col) {
  const int byte = (row * 128 + col * 2) ^ ((row & 7) << 4);
  return *reinterpret_cast<const bf16x8*>(reinterpret_cast<const char*>(base) + byte);
}
__device__ __forceinline__ void lds_write8(u16* base, int row, int col, bf16x8 v) {
  const int byte = (row * 128 + col * 2) ^ ((row & 7) << 4);
  *reinterpret_cast<bf16x8*>(reinterpret_cast<char*>(base) + byte) = v;
}
__device__ __forceinline__ void lds_write1(u16* base, int row, int col, u16 v) {
  const int byte = (row * 128 + col * 2) ^ ((row & 7) << 4);
  *reinterpret_cast<u16*>(reinterpret_cast<char*>(base) + byte) = v;
}

// ---------------------------------------------------------------------------
// Causal flash attention, GQA (4 q-heads / kv-head).
// Grid: (S/128, NH, B). Block 256 = 4 waves; wave owns 32 q-rows (2 m-frags).
// KBLK=64. K [64][64] and V^T [64][64] in swizzled LDS, staged via T14
// async split (issue loads -> compute -> barrier -> ds_write -> barrier).
// Per-wave P buffer [32][64] swizzled. Online softmax, 16-lane shfl reduce.
// ---------------------------------------------------------------------------
__global__ __launch_bounds__(256) void attn_kernel(
    const u16* __restrict__ Q, const u16* __restrict__ K,
    const u16* __restrict__ VT, u16* __restrict__ O)
{
  __shared__ u16 Ks[64 * 64];
  __shared__ u16 Vt[64 * 64];
  __shared__ u16 Pl[4][32 * 64];

  const int q0 = blockIdx.x * 128;
  const int h  = blockIdx.y;
  const int b  = blockIdx.z;
  const int kh = h >> 2;
  const int tid = threadIdx.x, wv = tid >> 6, lane = tid & 63;
  const int l15 = lane & 15, lhi = lane >> 4;
  const size_t qoff = (size_t)b * 2048 * 2048;
  const size_t koff = (size_t)b * 2048 * 512;

  const int sr0 = tid >> 3;          // staging row 0..31 (+32 for 2nd chunk)
  const int sc  = (tid & 7) * 8;     // staging col (x8)

  const int base = q0 + wv * 32;     // wave's first q-row

  // Q fragments: qf[m][kc], A-layout (row = l15, k = lhi*8+i)
  bf16x8 qf[2][2];
#pragma unroll
  for (int m = 0; m < 2; ++m)
#pragma unroll
    for (int kc = 0; kc < 2; ++kc)
      qf[m][kc] = *reinterpret_cast<const bf16x8*>(
          Q + qoff + (size_t)(base + m * 16 + l15) * 2048 + h * 64 + kc * 32 + lhi * 8);

  float mrun[2][4], lrun[2][4];
  f32x4 oacc[2][4] = {};
#pragma unroll
  for (int m = 0; m < 2; ++m)
#pragma unroll
    for (int r = 0; r < 4; ++r) { mrun[m][r] = -1e30f; lrun[m][r] = 0.f; }

  const int ntiles = (q0 + 128) / 64;

  // ---- prologue: stage tile 0 ----
  bf16x8 kv0, kv1, vt0, vt1;
  kv0 = *reinterpret_cast<const bf16x8*>(K + koff + (size_t)(sr0) * 512 + kh * 64 + sc);
  kv1 = *reinterpret_cast<const bf16x8*>(K + koff + (size_t)(sr0 + 32) * 512 + kh * 64 + sc);
  vt0 = *reinterpret_cast<const bf16x8*>(VT + (size_t)(kh * 64 + sr0) * 4096 + b * 2048 + sc);
  vt1 = *reinterpret_cast<const bf16x8*>(VT + (size_t)(kh * 64 + sr0 + 32) * 4096 + b * 2048 + sc);
  lds_write8(Ks, sr0, sc, kv0);
  lds_write8(Ks, sr0 + 32, sc, kv1);
  lds_write8(Vt, sr0, sc, vt0);
  lds_write8(Vt, sr0 + 32, sc, vt1);
  __syncthreads();

  for (int t = 0; t < ntiles; ++t) {
    const int t0 = t * 64;
    const bool more = (t + 1 < ntiles);
    // T14: issue next tile's global loads; latency hides under compute
    if (more) {
      const int n0 = t0 + 64;
      kv0 = *reinterpret_cast<const bf16x8*>(K + koff + (size_t)(n0 + sr0) * 512 + kh * 64 + sc);
      kv1 = *reinterpret_cast<const bf16x8*>(K + koff + (size_t)(n0 + sr0 + 32) * 512 + kh * 64 + sc);
      vt0 = *reinterpret_cast<const bf16x8*>(VT + (size_t)(kh * 64 + sr0) * 4096 + b * 2048 + n0 + sc);
      vt1 = *reinterpret_cast<const bf16x8*>(VT + (size_t)(kh * 64 + sr0 + 32) * 4096 + b * 2048 + n0 + sc);
    }

    if (t0 <= base + 31) {   // wave-uniform causal skip
      // ---- QK^T ----
      f32x4 s[2][4] = {};
#pragma unroll
      for (int kc = 0; kc < 2; ++kc) {
#pragma unroll
        for (int f = 0; f < 4; ++f) {
          const bf16x8 kf = lds_read8(Ks, f * 16 + l15, kc * 32 + lhi * 8);
          s[0][f] = __builtin_amdgcn_mfma_f32_16x16x32_bf16(qf[0][kc], kf, s[0][f], 0, 0, 0);
          s[1][f] = __builtin_amdgcn_mfma_f32_16x16x32_bf16(qf[1][kc], kf, s[1][f], 0, 0, 0);
        }
      }
      // ---- online softmax (per m-group of 16 q-rows) ----
#pragma unroll
      for (int m = 0; m < 2; ++m) {
        if (t0 > base + m * 16 + 15) continue;           // group fully masked
        const bool nm = (t0 + 63) > (base + m * 16);     // diagonal tile
#pragma unroll
        for (int rr = 0; rr < 4; ++rr) {
          const int qr = base + m * 16 + lhi * 4 + rr;
          float v[4];
#pragma unroll
          for (int f = 0; f < 4; ++f) {
            v[f] = s[m][f][rr] * 0.125f;
            if (nm && (t0 + f * 16 + l15 > qr)) v[f] = -1e30f;
          }
          float mx = fmaxf(fmaxf(v[0], v[1]), fmaxf(v[2], v[3]));
#pragma unroll
          for (int off = 1; off < 16; off <<= 1) mx = fmaxf(mx, __shfl_xor(mx, off));
          const float newm = fmaxf(mrun[m][rr], mx);
          const float fac = __expf(mrun[m][rr] - newm);
          float p[4], sum = 0.f;
#pragma unroll
          for (int f = 0; f < 4; ++f) { p[f] = __expf(v[f] - newm); sum += p[f]; }
#pragma unroll
          for (int off = 1; off < 16; off <<= 1) sum += __shfl_xor(sum, off);
          lrun[m][rr] = lrun[m][rr] * fac + sum;
          mrun[m][rr] = newm;
#pragma unroll
          for (int nf = 0; nf < 4; ++nf) oacc[m][nf][rr] *= fac;
#pragma unroll
          for (int f = 0; f < 4; ++f)
            lds_write1(Pl[wv], m * 16 + lhi * 4 + rr, f * 16 + l15, f2bf(p[f]));
        }
      }
      // ---- PV ----
#pragma unroll
      for (int kc = 0; kc < 2; ++kc) {
        bf16x8 vf[4];
#pragma unroll
        for (int nf = 0; nf < 4; ++nf)
          vf[nf] = lds_read8(Vt, nf * 16 + l15, kc * 32 + lhi * 8);
#pragma unroll
        for (int m = 0; m < 2; ++m) {
          if (t0 > base + m * 16 + 15) continue;
          const bf16x8 pf = lds_read8(Pl[wv], m * 16 + l15, kc * 32 + lhi * 8);
#pragma unroll
          for (int nf = 0; nf < 4; ++nf)
            oacc[m][nf] = __builtin_amdgcn_mfma_f32_16x16x32_bf16(pf, vf[nf], oacc[m][nf], 0, 0, 0);
        }
      }
    }

    __syncthreads();            // everyone done reading Ks/Vt
    if (more) {
      lds_write8(Ks, sr0, sc, kv0);
      lds_write8(Ks, sr0 + 32, sc, kv1);
      lds_write8(Vt, sr0, sc, vt0);
      lds_write8(Vt, sr0 + 32, sc, vt1);
    }
    __syncthreads();            // next tile staged
  }

  // ---- epilogue ----
#pragma unroll
  for (int m = 0; m < 2; ++m)
#pragma unroll
    for (int nf = 0; nf < 4; ++nf)
#pragma unroll
      for (int rr = 0; rr < 4; ++rr) {
        const int qr = base + m * 16 + lhi * 4 + rr;
        O[qoff + (size_t)qr * 2048 + h * 64 + nf * 16 + l15] =
            f2bf(oacc[m][nf][rr] / lrun[m][rr]);
      }
}

// ---------------------------------------------------------------------------
extern "C" void kernel_launch(void* const* d_in, const int* in_sizes, int n_in,
                              void* d_out, int out_size, void* d_ws, size_t ws_size,
                              hipStream_t stream)
{
  const float* x  = (const float*)d_in[0];
  const float* fc = (const float*)d_in[1];
  const float* fs = (const float*)d_in[2];
  // d_in[3] = mask (causal; analytic)
  const float* wq = (const float*)d_in[4];
  const float* wk = (const float*)d_in[5];
  const float* wv = (const float*)d_in[6];
  const float* wo = (const float*)d_in[7];
  float* out = (float*)d_out;

  u16* Xb  = (u16*)d_ws;                          // 4096 x 2048
  u16* Wqb = Xb  + (size_t)4096 * 2048;           // 2048 x 2048
  u16* Wkb = Wqb + (size_t)2048 * 2048;           // 512 x 2048
  u16* Wvb = Wkb + (size_t)512 * 2048;            // 512 x 2048
  u16* Qws = Wvb + (size_t)512 * 2048;            // 4096 x 2048
  u16* Kws = Qws + (size_t)4096 * 2048;           // 4096 x 512
  u16* VTws = Kws + (size_t)4096 * 512;           // 512 x 4096  (V transposed)
  u16* Ows = Xb;                                  // alias: x dead after QKV
  u16* Wob = Wqb;                                 // alias: wq dead after Q gemm

  dim3 blk(256);
  f32_to_bf16<<<dim3(4096 * 2048 / 8 / 256), blk, 0, stream>>>(x,  Xb,  4096 * 2048);
  f32_to_bf16<<<dim3(2048 * 2048 / 8 / 256), blk, 0, stream>>>(wq, Wqb, 2048 * 2048);
  f32_to_bf16<<<dim3(512 * 2048 / 8 / 256),  blk, 0, stream>>>(wk, Wkb, 512 * 2048);
  f32_to_bf16<<<dim3(512 * 2048 / 8 / 256),  blk, 0, stream>>>(wv, Wvb, 512 * 2048);
  // QKV projections
  gemm_bt<0,0><<<dim3(16, 32), blk, 0, stream>>>(Xb, Wqb, Qws, 2048, 2048, 2048);
  gemm_bt<0,0><<<dim3(4, 32),  blk, 0, stream>>>(Xb, Wkb, Kws, 512, 2048, 512);
  gemm_bt<0,1><<<dim3(4, 32),  blk, 0, stream>>>(Xb, Wvb, VTws, 512, 2048, 4096); // V^T
  f32_to_bf16<<<dim3(2048 * 2048 / 8 / 256), blk, 0, stream>>>(wo, Wob, 2048 * 2048);
  rope_kernel<<<dim3((4096 * 2048 / 8 + 4096 * 512 / 8) / 256), blk, 0, stream>>>(Qws, Kws, fc, fs);
  // Flash attention
  attn_kernel<<<dim3(16, 32, 2), blk, 0, stream>>>(Qws, Kws, VTws, Ows);
  // Output projection -> f32
  gemm_bt<1,0><<<dim3(16, 32), blk, 0, stream>>>(Ows, Wob, out, 2048, 2048, 2048);
}

// Round 4
// 411.337 us; speedup vs baseline: 1.4058x; 1.2036x over previous
//
#include <hip/hip_runtime.h>
#include <hip/hip_bf16.h>
#include <stdint.h>

typedef __bf16 bf16x8 __attribute__((ext_vector_type(8)));
typedef float f32x4 __attribute__((ext_vector_type(4)));
typedef unsigned short u16;
typedef u16 u16x8 __attribute__((ext_vector_type(8)));

__device__ __forceinline__ float bf2f(u16 u) {
  union { uint32_t i; float f; } v; v.i = uint32_t(u) << 16; return v.f;
}
__device__ __forceinline__ u16 f2bf(float f) {
  union { float f; uint32_t i; } v; v.f = f;
  uint32_t r = v.i + 0x7FFFu + ((v.i >> 16) & 1u);  // RNE
  return (u16)(r >> 16);
}
__device__ __forceinline__ uint32_t pack2(float a, float b) {
  union { __bf16 h[2]; uint32_t u; } v;
  v.h[0] = (__bf16)a; v.h[1] = (__bf16)b; return v.u;
}

// ---------------------------------------------------------------------------
// f32 -> bf16 conversion
// ---------------------------------------------------------------------------
__global__ __launch_bounds__(256) void f32_to_bf16(
    const float* __restrict__ in, u16* __restrict__ out, int n)
{
  const int i = (blockIdx.x * 256 + threadIdx.x) * 8;
  if (i >= n) return;
  const float4 a = *reinterpret_cast<const float4*>(in + i);
  const float4 b = *reinterpret_cast<const float4*>(in + i + 4);
  u16x8 o;
  o[0] = f2bf(a.x); o[1] = f2bf(a.y); o[2] = f2bf(a.z); o[3] = f2bf(a.w);
  o[4] = f2bf(b.x); o[5] = f2bf(b.y); o[6] = f2bf(b.z); o[7] = f2bf(b.w);
  *reinterpret_cast<u16x8*>(out + i) = o;
}

// ---------------------------------------------------------------------------
// GEMM: C[M,N] = A[M,K] * B[N,K]^T   (bf16 in, f32 acc)
// ---------------------------------------------------------------------------
#define BM 128
#define BN 128
#define BK 32
#define LDS_STR 40

template <int F32OUT, int TRANSC>
__global__ __launch_bounds__(256) void gemm_bt(
    const u16* __restrict__ A, const u16* __restrict__ Bw, void* __restrict__ Cv,
    int N, int K, int ldc)
{
  __shared__ u16 As[BM * LDS_STR];
  __shared__ u16 Bs[BN * LDS_STR];
  const int tid = threadIdx.x;
  const int row0 = blockIdx.y * BM, col0 = blockIdx.x * BN;
  const int wv = tid >> 6, lane = tid & 63;
  const int wr = (wv >> 1) * 64, wc = (wv & 1) * 64;
  const int l15 = lane & 15, lk = (lane >> 4) * 8;
  const int srow = tid >> 2, sk = (tid & 3) * 8;

  f32x4 acc[4][4] = {};

  for (int k0 = 0; k0 < K; k0 += BK) {
    bf16x8 av0 = *reinterpret_cast<const bf16x8*>(A + (size_t)(row0 + srow) * K + k0 + sk);
    bf16x8 av1 = *reinterpret_cast<const bf16x8*>(A + (size_t)(row0 + srow + 64) * K + k0 + sk);
    bf16x8 bv0 = *reinterpret_cast<const bf16x8*>(Bw + (size_t)(col0 + srow) * K + k0 + sk);
    bf16x8 bv1 = *reinterpret_cast<const bf16x8*>(Bw + (size_t)(col0 + srow + 64) * K + k0 + sk);
    *reinterpret_cast<bf16x8*>(As + srow * LDS_STR + sk) = av0;
    *reinterpret_cast<bf16x8*>(As + (srow + 64) * LDS_STR + sk) = av1;
    *reinterpret_cast<bf16x8*>(Bs + srow * LDS_STR + sk) = bv0;
    *reinterpret_cast<bf16x8*>(Bs + (srow + 64) * LDS_STR + sk) = bv1;
    __syncthreads();

    bf16x8 af[4], bfv[4];
#pragma unroll
    for (int i = 0; i < 4; ++i)
      af[i] = *reinterpret_cast<const bf16x8*>(As + (wr + i * 16 + l15) * LDS_STR + lk);
#pragma unroll
    for (int i = 0; i < 4; ++i)
      bfv[i] = *reinterpret_cast<const bf16x8*>(Bs + (wc + i * 16 + l15) * LDS_STR + lk);
#pragma unroll
    for (int mi = 0; mi < 4; ++mi)
#pragma unroll
      for (int ni = 0; ni < 4; ++ni)
        acc[mi][ni] = __builtin_amdgcn_mfma_f32_16x16x32_bf16(af[mi], bfv[ni], acc[mi][ni], 0, 0, 0);
    __syncthreads();
  }

#pragma unroll
  for (int mi = 0; mi < 4; ++mi) {
    const int r0 = row0 + wr + mi * 16 + (lane >> 4) * 4;
#pragma unroll
    for (int ni = 0; ni < 4; ++ni) {
      const int c = col0 + wc + ni * 16 + l15;
#pragma unroll
      for (int r = 0; r < 4; ++r) {
        if (TRANSC)
          reinterpret_cast<u16*>(Cv)[(size_t)c * ldc + (r0 + r)] = f2bf(acc[mi][ni][r]);
        else if (F32OUT)
          reinterpret_cast<float*>(Cv)[(size_t)(r0 + r) * ldc + c] = acc[mi][ni][r];
        else
          reinterpret_cast<u16*>(Cv)[(size_t)(r0 + r) * ldc + c] = f2bf(acc[mi][ni][r]);
      }
    }
  }
}

// ---------------------------------------------------------------------------
// RoPE, in-place on Q (4096x2048) then K (4096x512).
// ---------------------------------------------------------------------------
__global__ __launch_bounds__(256) void rope_kernel(
    u16* __restrict__ Q, u16* __restrict__ Kv,
    const float* __restrict__ cosb, const float* __restrict__ sinb)
{
  const int QV = 4096 * 2048 / 8;
  const int KV = 4096 * 512 / 8;
  int t = blockIdx.x * 256 + threadIdx.x;
  u16* ptr; int shift;
  if (t < QV) { ptr = Q; shift = 11; }
  else { t -= QV; if (t >= KV) return; ptr = Kv; shift = 9; }
  const int e = t * 8;
  const int row = e >> shift;
  const int col = e & ((1 << shift) - 1);
  const int s = row & 2047;
  const int j0 = (col & 63) >> 1;
  u16* p = ptr + ((size_t)row << shift) + col;
  u16x8 x = *reinterpret_cast<const u16x8*>(p);
  u16x8 o;
#pragma unroll
  for (int q = 0; q < 4; ++q) {
    const float c  = cosb[s * 32 + j0 + q];
    const float sn = sinb[s * 32 + j0 + q];
    const float xr = bf2f(x[2 * q]), xi = bf2f(x[2 * q + 1]);
    o[2 * q]     = f2bf(xr * c - xi * sn);
    o[2 * q + 1] = f2bf(xr * sn + xi * c);
  }
  *reinterpret_cast<u16x8*>(p) = o;
}

// ---------------------------------------------------------------------------
// Swizzled-LDS helpers: tiles [rows][64] bf16, row stride 128B,
// byte ^= ((row&7)<<4)
// ---------------------------------------------------------------------------
__device__ __forceinline__ bf16x8 lds_read8(const u16* base, int row, int col) {
  const int byte = (row * 128 + col * 2) ^ ((row & 7) << 4);
  return *reinterpret_cast<const bf16x8*>(reinterpret_cast<const char*>(base) + byte);
}
__device__ __forceinline__ void lds_write8(u16* base, int row, int col, bf16x8 v) {
  const int byte = (row * 128 + col * 2) ^ ((row & 7) << 4);
  *reinterpret_cast<bf16x8*>(reinterpret_cast<char*>(base) + byte) = v;
}
__device__ __forceinline__ void lds_write4(u16* base, int row, int col, uint32_t v) {
  const int byte = (row * 128 + col * 2) ^ ((row & 7) << 4);
  *reinterpret_cast<uint32_t*>(reinterpret_cast<char*>(base) + byte) = v;
}

__device__ __forceinline__ bf16x8 scale8(bf16x8 v) {
#pragma unroll
  for (int i = 0; i < 8; ++i) v[i] = (__bf16)((float)v[i] * 0.125f);
  return v;
}

// ---------------------------------------------------------------------------
// One q-set (16 rows) update vs one 64-kv tile.
// Swapped QK^T: S^T = mfma(K_frag, Q_frag); lane (l15=q, lhi) holds
// S[k = t0+16f+4*lhi+r][q]. In-register softmax: in-lane tree + 2 shfl.
// P relayout via per-wave swizzled LDS buffer (no barrier needed).
// ---------------------------------------------------------------------------
__device__ __forceinline__ void attn_set(
    const u16* __restrict__ Ks, const u16* __restrict__ Vt, u16* __restrict__ Plw,
    const bf16x8 qf[2], const int t0, const int qbase,
    const int l15, const int lhi,
    float& mrun, float& lrun, f32x4 oacc[4])
{
  // QK^T (swapped): A = K rows (lane row = k), B = Q (lane col = q)
  f32x4 s[4] = {};
#pragma unroll
  for (int kc = 0; kc < 2; ++kc)
#pragma unroll
    for (int f = 0; f < 4; ++f) {
      const bf16x8 kf = lds_read8(Ks, f * 16 + l15, kc * 32 + lhi * 8);
      s[f] = __builtin_amdgcn_mfma_f32_16x16x32_bf16(kf, qf[kc], s[f], 0, 0, 0);
    }
  // mask + row max (row = q = l15; scores spread over 4 lanes lhi)
  const bool needmask = (t0 + 63 > qbase);
  float v[4][4];
  float mx = -1e30f;
#pragma unroll
  for (int f = 0; f < 4; ++f)
#pragma unroll
    for (int r = 0; r < 4; ++r) {
      float x = s[f][r];
      if (needmask && (t0 + f * 16 + lhi * 4 + r > qbase + l15)) x = -1e30f;
      v[f][r] = x;
      mx = fmaxf(mx, x);
    }
  mx = fmaxf(mx, __shfl_xor(mx, 16));
  mx = fmaxf(mx, __shfl_xor(mx, 32));
  const float newm = fmaxf(mrun, mx);
  const float fac = __expf(mrun - newm);
  mrun = newm;
  float sum = 0.f;
#pragma unroll
  for (int f = 0; f < 4; ++f) {
    const float p0 = __expf(v[f][0] - newm), p1 = __expf(v[f][1] - newm);
    const float p2 = __expf(v[f][2] - newm), p3 = __expf(v[f][3] - newm);
    sum += (p0 + p1) + (p2 + p3);
    lds_write4(Plw, l15, f * 16 + lhi * 4,     pack2(p0, p1));
    lds_write4(Plw, l15, f * 16 + lhi * 4 + 2, pack2(p2, p3));
  }
  sum += __shfl_xor(sum, 16);
  sum += __shfl_xor(sum, 32);
  lrun = lrun * fac + sum;
  // rescale O (O rows = q = 4*lhi+r; fac lives at lane l15=q)
  float facq[4];
#pragma unroll
  for (int r = 0; r < 4; ++r) facq[r] = __shfl(fac, lhi * 4 + r);
#pragma unroll
  for (int nf = 0; nf < 4; ++nf) {
    f32x4 t = oacc[nf];
#pragma unroll
    for (int r = 0; r < 4; ++r) t[r] *= facq[r];
    oacc[nf] = t;
  }
  // PV: A = P (lane row = q = l15), B = V (lane col = d)
#pragma unroll
  for (int kc = 0; kc < 2; ++kc) {
    const bf16x8 pa = lds_read8(Plw, l15, kc * 32 + lhi * 8);
#pragma unroll
    for (int nf = 0; nf < 4; ++nf) {
      const bf16x8 vf = lds_read8(Vt, nf * 16 + l15, kc * 32 + lhi * 8);
      oacc[nf] = __builtin_amdgcn_mfma_f32_16x16x32_bf16(pa, vf, oacc[nf], 0, 0, 0);
    }
  }
}

__device__ __forceinline__ void attn_store(
    u16* __restrict__ O, const size_t qoff, const int h, const int qbase,
    const int l15, const int lhi, const float lrun, const f32x4 oacc[4])
{
  float linv[4];
#pragma unroll
  for (int r = 0; r < 4; ++r) linv[r] = 1.f / __shfl(lrun, lhi * 4 + r);
#pragma unroll
  for (int nf = 0; nf < 4; ++nf)
#pragma unroll
    for (int r = 0; r < 4; ++r)
      O[qoff + (size_t)(qbase + lhi * 4 + r) * 2048 + h * 64 + nf * 16 + l15] =
          f2bf(oacc[nf][r] * linv[r]);
}

// ---------------------------------------------------------------------------
// Causal flash attention, GQA. Grid (16, 32, 2); block 256 = 4 waves.
// Balanced pairing: block j handles q-tile j (rows 64j..) AND q-tile 31-j.
// Every block does exactly 33 set-tile updates. Wave owns 16 q-rows per set.
// K [64][64] + V^T [64][64] swizzled LDS, T14 async staging.
// ---------------------------------------------------------------------------
__global__ __launch_bounds__(256, 4) void attn_kernel(
    const u16* __restrict__ Q, const u16* __restrict__ K,
    const u16* __restrict__ VT, u16* __restrict__ O)
{
  __shared__ u16 Ks[64 * 64];
  __shared__ u16 Vt[64 * 64];
  __shared__ u16 Pl[4][16 * 64];

  const int j  = blockIdx.x;            // 0..15
  const int h  = blockIdx.y;
  const int b  = blockIdx.z;
  const int kh = h >> 2;
  const int tid = threadIdx.x, wv = tid >> 6, lane = tid & 63;
  const int l15 = lane & 15, lhi = lane >> 4;
  const size_t qoff = (size_t)b * 2048 * 2048;
  const size_t koff = (size_t)b * 2048 * 512;

  const int qAb = j * 64 + wv * 16;
  const int qBb = (31 - j) * 64 + wv * 16;

  const int sr0 = tid >> 3;           // 0..31
  const int sc  = (tid & 7) * 8;

  // Q fragments pre-scaled by 1/8 (exact in bf16)
  bf16x8 qfA[2], qfB[2];
#pragma unroll
  for (int kc = 0; kc < 2; ++kc) {
    qfA[kc] = scale8(*reinterpret_cast<const bf16x8*>(
        Q + qoff + (size_t)(qAb + l15) * 2048 + h * 64 + kc * 32 + lhi * 8));
    qfB[kc] = scale8(*reinterpret_cast<const bf16x8*>(
        Q + qoff + (size_t)(qBb + l15) * 2048 + h * 64 + kc * 32 + lhi * 8));
  }

  float mA = -1e30f, lA = 0.f, mB = -1e30f, lB = 0.f;
  f32x4 oA[4] = {}, oB[4] = {};

  const int tlast = 31 - j;

  // prologue: stage tile 0
  bf16x8 kv0, kv1, vt0, vt1;
  kv0 = *reinterpret_cast<const bf16x8*>(K + koff + (size_t)(sr0) * 512 + kh * 64 + sc);
  kv1 = *reinterpret_cast<const bf16x8*>(K + koff + (size_t)(sr0 + 32) * 512 + kh * 64 + sc);
  vt0 = *reinterpret_cast<const bf16x8*>(VT + (size_t)(kh * 64 + sr0) * 4096 + b * 2048 + sc);
  vt1 = *reinterpret_cast<const bf16x8*>(VT + (size_t)(kh * 64 + sr0 + 32) * 4096 + b * 2048 + sc);
  lds_write8(Ks, sr0, sc, kv0);
  lds_write8(Ks, sr0 + 32, sc, kv1);
  lds_write8(Vt, sr0, sc, vt0);
  lds_write8(Vt, sr0 + 32, sc, vt1);
  __syncthreads();

  for (int t = 0; t <= tlast; ++t) {
    const int t0 = t * 64;
    const bool more = t < tlast;
    if (more) {
      const int n0 = t0 + 64;
      kv0 = *reinterpret_cast<const bf16x8*>(K + koff + (size_t)(n0 + sr0) * 512 + kh * 64 + sc);
      kv1 = *reinterpret_cast<const bf16x8*>(K + koff + (size_t)(n0 + sr0 + 32) * 512 + kh * 64 + sc);
      vt0 = *reinterpret_cast<const bf16x8*>(VT + (size_t)(kh * 64 + sr0) * 4096 + b * 2048 + n0 + sc);
      vt1 = *reinterpret_cast<const bf16x8*>(VT + (size_t)(kh * 64 + sr0 + 32) * 4096 + b * 2048 + n0 + sc);
    }

    if (t <= j)
      attn_set(Ks, Vt, Pl[wv], qfA, t0, qAb, l15, lhi, mA, lA, oA);
    attn_set(Ks, Vt, Pl[wv], qfB, t0, qBb, l15, lhi, mB, lB, oB);

    __syncthreads();
    if (more) {
      lds_write8(Ks, sr0, sc, kv0);
      lds_write8(Ks, sr0 + 32, sc, kv1);
      lds_write8(Vt, sr0, sc, vt0);
      lds_write8(Vt, sr0 + 32, sc, vt1);
    }
    __syncthreads();
  }

  attn_store(O, qoff, h, qAb, l15, lhi, lA, oA);
  attn_store(O, qoff, h, qBb, l15, lhi, lB, oB);
}

// ---------------------------------------------------------------------------
extern "C" void kernel_launch(void* const* d_in, const int* in_sizes, int n_in,
                              void* d_out, int out_size, void* d_ws, size_t ws_size,
                              hipStream_t stream)
{
  const float* x  = (const float*)d_in[0];
  const float* fc = (const float*)d_in[1];
  const float* fs = (const float*)d_in[2];
  // d_in[3] = mask (causal; analytic)
  const float* wq = (const float*)d_in[4];
  const float* wk = (const float*)d_in[5];
  const float* wv = (const float*)d_in[6];
  const float* wo = (const float*)d_in[7];
  float* out = (float*)d_out;

  u16* Xb  = (u16*)d_ws;                          // 4096 x 2048
  u16* Wqb = Xb  + (size_t)4096 * 2048;           // 2048 x 2048
  u16* Wkb = Wqb + (size_t)2048 * 2048;           // 512 x 2048
  u16* Wvb = Wkb + (size_t)512 * 2048;            // 512 x 2048
  u16* Qws = Wvb + (size_t)512 * 2048;            // 4096 x 2048
  u16* Kws = Qws + (size_t)4096 * 2048;           // 4096 x 512
  u16* VTws = Kws + (size_t)4096 * 512;           // 512 x 4096  (V transposed)
  u16* Ows = Xb;                                  // alias: x dead after QKV
  u16* Wob = Wqb;                                 // alias: wq dead after Q gemm

  dim3 blk(256);
  f32_to_bf16<<<dim3(4096 * 2048 / 8 / 256), blk, 0, stream>>>(x,  Xb,  4096 * 2048);
  f32_to_bf16<<<dim3(2048 * 2048 / 8 / 256), blk, 0, stream>>>(wq, Wqb, 2048 * 2048);
  f32_to_bf16<<<dim3(512 * 2048 / 8 / 256),  blk, 0, stream>>>(wk, Wkb, 512 * 2048);
  f32_to_bf16<<<dim3(512 * 2048 / 8 / 256),  blk, 0, stream>>>(wv, Wvb, 512 * 2048);
  // QKV projections
  gemm_bt<0,0><<<dim3(16, 32), blk, 0, stream>>>(Xb, Wqb, Qws, 2048, 2048, 2048);
  gemm_bt<0,0><<<dim3(4, 32),  blk, 0, stream>>>(Xb, Wkb, Kws, 512, 2048, 512);
  gemm_bt<0,1><<<dim3(4, 32),  blk, 0, stream>>>(Xb, Wvb, VTws, 512, 2048, 4096); // V^T
  f32_to_bf16<<<dim3(2048 * 2048 / 8 / 256), blk, 0, stream>>>(wo, Wob, 2048 * 2048);
  rope_kernel<<<dim3((4096 * 2048 / 8 + 4096 * 512 / 8) / 256), blk, 0, stream>>>(Qws, Kws, fc, fs);
  // Flash attention
  attn_kernel<<<dim3(16, 32, 2), blk, 0, stream>>>(Qws, Kws, VTws, Ows);
  // Output projection -> f32
  gemm_bt<1,0><<<dim3(16, 32), blk, 0, stream>>>(Ows, Wob, out, 2048, 2048, 2048);
}